// Round 1
// baseline (129.267 us; speedup 1.0000x reference)
//
#include <hip/hip_runtime.h>

// Stein layer: B=65536, D=32, H=128
// out[r] = -x_r·u(x_r) + div u(x_r) + theta0
//   u(x) = tanh(x W1 + b1) W2 + b2
//   div u = sum_k (1 - h_k^2) c_k,  c_k = sum_i W1[i,k] W2[k,i]
//   -x·u  = -sum_k h_k v_k - x·b2,  v_k = sum_j W2[k,j] x_j

#define NROWS 65536
#define D 32
#define H 128

// Precompute c_k = sum_i W1[i,k] * W2[k,i]  (128 floats into d_ws)
__global__ void stein_ck_kernel(const float* __restrict__ W1,
                                const float* __restrict__ W2,
                                float* __restrict__ c) {
    int k = threadIdx.x;  // 128 threads
    float acc = 0.f;
#pragma unroll
    for (int i = 0; i < D; ++i)
        acc = fmaf(W1[i * H + k], W2[k * D + i], acc);
    c[k] = acc;
}

// Block = 256 threads = 4 waves. Each wave handles the SAME 64 rows but a
// different 32-wide k-slice (wave-uniform weight indices -> s_load path).
__global__ __launch_bounds__(256) void stein_main_kernel(
    const float* __restrict__ x, const float* __restrict__ W1,
    const float* __restrict__ b1, const float* __restrict__ W2,
    const float* __restrict__ b2, const float* __restrict__ theta,
    const float* __restrict__ c, float* __restrict__ out) {
    __shared__ float part[4][64];

    const int tid = threadIdx.x;
    const int lane = tid & 63;
    const int kq = tid >> 6;                 // wave id: which k-slice
    const int row = blockIdx.x * 64 + lane;  // grid is exact: 1024*64 = 65536

    // Load this row's x into registers (8 x float4, 128B per lane).
    float xv[D];
    const float4* xr = (const float4*)(x + (size_t)row * D);
#pragma unroll
    for (int i = 0; i < 8; ++i) {
        float4 t = xr[i];
        xv[4 * i + 0] = t.x;
        xv[4 * i + 1] = t.y;
        xv[4 * i + 2] = t.z;
        xv[4 * i + 3] = t.w;
    }

    float s = 0.f;
    const int kbase = kq * 32;
#pragma unroll 4
    for (int kk = 0; kk < 32; ++kk) {
        const int k = kbase + kk;
        float z = b1[k];  // wave-uniform load
        float v = 0.f;
#pragma unroll
        for (int i = 0; i < D; ++i) {
            z = fmaf(xv[i], W1[i * H + k], z);  // uniform weight, per-lane x
            v = fmaf(xv[i], W2[k * D + i], v);
        }
        // tanh(z) = (e^{2z}-1)/(e^{2z}+1), clamp avoids inf/inf
        float zz = fminf(fmaxf(z, -15.f), 15.f);
        float e = __expf(2.f * zz);
        float h = (e - 1.f) * __builtin_amdgcn_rcpf(e + 1.f);
        float ck = c[k];
        s += ck - h * fmaf(h, ck, v);  // c_k - h^2 c_k - h v_k
    }

    if (kq == 0) {  // fold per-row constant terms into slice 0's partial
        float dot = 0.f;
#pragma unroll
        for (int i = 0; i < D; ++i) dot = fmaf(xv[i], b2[i], dot);
        s += theta[0] - dot;
    }

    part[kq][lane] = s;
    __syncthreads();
    if (tid < 64) {
        out[row] = (part[0][tid] + part[1][tid]) + (part[2][tid] + part[3][tid]);
    }
}

extern "C" void kernel_launch(void* const* d_in, const int* in_sizes, int n_in,
                              void* d_out, int out_size, void* d_ws, size_t ws_size,
                              hipStream_t stream) {
    const float* x = (const float*)d_in[0];
    const float* W1 = (const float*)d_in[1];
    const float* b1 = (const float*)d_in[2];
    const float* W2 = (const float*)d_in[3];
    const float* b2 = (const float*)d_in[4];
    const float* theta = (const float*)d_in[5];
    float* out = (float*)d_out;
    float* c = (float*)d_ws;  // 128 floats

    stein_ck_kernel<<<1, H, 0, stream>>>(W1, W2, c);
    stein_main_kernel<<<NROWS / 64, 256, 0, stream>>>(x, W1, b1, W2, b2, theta,
                                                      c, out);
}

// Round 2
// 73.512 us; speedup vs baseline: 1.7584x; 1.7584x over previous
//
#include <hip/hip_runtime.h>

// Stein layer via MFMA: B=65536, D=32, H=128
// out[r] = sum_k [ c_k - h_k*(h_k*c_k + v_k) ] - x.b2 + theta0
//   z = x W1 + b1 (dual-bf16 MFMA, K=32=D in one shot), h = tanh(z)
//   v_k = sum_d x_d W2[k,d]  (single-bf16 MFMA vs W2^T)
//   c_k = sum_i W1[i,k] W2[k,i]  (fp32, precomputed)
//   x.b2 folded in as column 128 of the augmented W2^T (9th V tile)

#define NROWS 65536
#define DD 32
#define HH 128
#define NTILE 25  // 8 W1hi + 8 W1lo + 9 W2T(+b2 ext)

typedef __attribute__((ext_vector_type(8))) short short8;
typedef __attribute__((ext_vector_type(4))) float f32x4;

static __device__ __forceinline__ unsigned short f2bf(float f) {
    unsigned u = __float_as_uint(f);
    u += 0x7fff + ((u >> 16) & 1);  // round-to-nearest-even
    return (unsigned short)(u >> 16);
}
static __device__ __forceinline__ float bf2f(unsigned short h) {
    return __uint_as_float(((unsigned)h) << 16);
}

// Pack weights into MFMA B-fragment order: packed[tile][lane][j] (ushort),
// B[k][n] with n = tile_col*16 + (lane&15), k = (lane>>4)*8 + j.
// Tiles 0..7:  W1 hi (n-tile t)         Tiles 8..15: W1 lo
// Tiles 16..24: W2T[d][n] = W2[n][d]; tile 24 col 128 = b2, cols 129..143 = 0
// Block 25 computes c_k in fp32.
__global__ __launch_bounds__(256) void stein_pack(
    const float* __restrict__ W1, const float* __restrict__ W2,
    const float* __restrict__ b2, unsigned short* __restrict__ packed,
    float* __restrict__ c) {
    const int blk = blockIdx.x;
    if (blk < NTILE) {
        for (int idx = threadIdx.x; idx < 512; idx += 256) {
            const int l = idx >> 3, j = idx & 7;
            const int k = (l >> 4) * 8 + j;  // K index (d), 0..31
            const int cc = l & 15;
            unsigned short val;
            if (blk < 8) {  // W1 hi
                val = f2bf(W1[k * HH + blk * 16 + cc]);
            } else if (blk < 16) {  // W1 lo (residual)
                float w = W1[k * HH + (blk - 8) * 16 + cc];
                val = f2bf(w - bf2f(f2bf(w)));
            } else {  // W2T augmented
                const int n = (blk - 16) * 16 + cc;
                float w = (n < HH) ? W2[n * DD + k] : ((n == HH) ? b2[k] : 0.f);
                val = f2bf(w);
            }
            packed[blk * 512 + idx] = val;
        }
    } else {
        const int k = threadIdx.x;
        if (k < HH) {
            float acc = 0.f;
#pragma unroll
            for (int i = 0; i < DD; ++i)
                acc = fmaf(W1[i * HH + k], W2[k * DD + i], acc);
            c[k] = acc;
        }
    }
}

__global__ __launch_bounds__(256) void stein_main(
    const float* __restrict__ x, const float* __restrict__ b1,
    const float* __restrict__ theta, const unsigned short* __restrict__ packed,
    const float* __restrict__ c, float* __restrict__ out) {
    __shared__ unsigned short lb[NTILE * 512];

    // Stage all packed B-fragments (25.6 KB) into LDS, coalesced float4.
    {
        const float4* src = (const float4*)packed;
        float4* dst = (float4*)lb;
        for (int i = threadIdx.x; i < NTILE * 512 / 8; i += 256) dst[i] = src[i];
    }
    __syncthreads();

    const int lane = threadIdx.x & 63;
    const int wv = threadIdx.x >> 6;
    const int quad = lane >> 4;
    const int cl = lane & 15;
    const int rowbase = blockIdx.x * 64 + wv * 16;  // 1024 blocks x 4 waves x 16 rows

    // A fragment: A[m][k], m = lane&15 (row), k = quad*8+j. 8 consecutive fp32.
    const float* xr = x + (size_t)(rowbase + cl) * DD + quad * 8;
    const float4 x0 = *(const float4*)xr;
    const float4 x1 = *(const float4*)(xr + 4);
    const float xv[8] = {x0.x, x0.y, x0.z, x0.w, x1.x, x1.y, x1.z, x1.w};
    short8 aHi, aLo;
#pragma unroll
    for (int j = 0; j < 8; ++j) {
        const unsigned short h = f2bf(xv[j]);
        aHi[j] = (short)h;
        aLo[j] = (short)f2bf(xv[j] - bf2f(h));
    }

    // Per-column constants (cl is the output column within each n-tile).
    float ckv[8], b1v[8];
#pragma unroll
    for (int t = 0; t < 8; ++t) {
        ckv[t] = c[t * 16 + cl];
        b1v[t] = b1[t * 16 + cl];
    }

    const f32x4 zero = {0.f, 0.f, 0.f, 0.f};
    float sa[4] = {0.f, 0.f, 0.f, 0.f};

#pragma unroll
    for (int t = 0; t < 8; ++t) {
        const short8 bH = *(const short8*)(lb + t * 512 + lane * 8);
        const short8 bL = *(const short8*)(lb + (8 + t) * 512 + lane * 8);
        const short8 bW = *(const short8*)(lb + (16 + t) * 512 + lane * 8);
        f32x4 z = zero;
        z = __builtin_amdgcn_mfma_f32_16x16x32_bf16(aLo, bH, z, 0, 0, 0);
        z = __builtin_amdgcn_mfma_f32_16x16x32_bf16(aHi, bL, z, 0, 0, 0);
        z = __builtin_amdgcn_mfma_f32_16x16x32_bf16(aHi, bH, z, 0, 0, 0);
        const f32x4 v = __builtin_amdgcn_mfma_f32_16x16x32_bf16(aHi, bW, zero, 0, 0, 0);
#pragma unroll
        for (int r = 0; r < 4; ++r) {
            float zz = z[r] + b1v[t];
            zz = fminf(fmaxf(zz, -15.f), 15.f);
            const float e = __expf(2.f * zz);
            const float h = fmaf(-2.f, __builtin_amdgcn_rcpf(e + 1.f), 1.f);
            const float ck = ckv[t];
            sa[r] += ck - h * fmaf(h, ck, v[r]);  // c_k - h^2 c_k - h v_k
        }
    }
    // Augmented tile: v = x.b2 in col 128 (cl==0); other cols are exact zeros.
    {
        const short8 bW = *(const short8*)(lb + 24 * 512 + lane * 8);
        const f32x4 v = __builtin_amdgcn_mfma_f32_16x16x32_bf16(aHi, bW, zero, 0, 0, 0);
#pragma unroll
        for (int r = 0; r < 4; ++r) sa[r] -= v[r];
    }

    // Reduce the 16 columns per row (xor within the low 4 lane bits).
#pragma unroll
    for (int r = 0; r < 4; ++r) {
#pragma unroll
        for (int m = 1; m < 16; m <<= 1) sa[r] += __shfl_xor(sa[r], m, 64);
    }

    // C/D rows: row = quad*4 + reg -> 4 consecutive rows per storing lane.
    if (cl == 0) {
        const float th = theta[0];
        float4 o;
        o.x = sa[0] + th;
        o.y = sa[1] + th;
        o.z = sa[2] + th;
        o.w = sa[3] + th;
        *(float4*)(out + rowbase + quad * 4) = o;
    }
}

extern "C" void kernel_launch(void* const* d_in, const int* in_sizes, int n_in,
                              void* d_out, int out_size, void* d_ws, size_t ws_size,
                              hipStream_t stream) {
    const float* x = (const float*)d_in[0];
    const float* W1 = (const float*)d_in[1];
    const float* b1 = (const float*)d_in[2];
    const float* W2 = (const float*)d_in[3];
    const float* b2 = (const float*)d_in[4];
    const float* theta = (const float*)d_in[5];
    float* out = (float*)d_out;

    unsigned short* packed = (unsigned short*)d_ws;       // 25*512 ushort = 25.6 KB
    float* c = (float*)((char*)d_ws + NTILE * 512 * 2);   // 128 fp32

    stein_pack<<<NTILE + 1, 256, 0, stream>>>(W1, W2, b2, packed, c);
    stein_main<<<NROWS / 64, 256, 0, stream>>>(x, b1, theta, packed, c, out);
}

// Round 3
// 72.025 us; speedup vs baseline: 1.7947x; 1.0206x over previous
//
#include <hip/hip_runtime.h>

// Stein layer, fully fused single kernel. B=65536, D=32, H=128.
// out[r] = sum_k [ c_k - h_k*(h_k*c_k + v_k) ] - x.b2 + theta0
//   z = x W1 + b1 (dual-bf16 MFMA: aHi*bHi + aHi*bLo + aLo*bHi), h = tanh(z)
//   v = x W2^T (single bf16 MFMA); x.b2 via augmented col 128 of W2^T
//   c_k = sum_i W1[i,k] W2[k,i] (fp32, computed per-block during pack)
// Each block: 512 threads = 8 waves = 128 rows. Pack phase builds all 25
// B-fragment tiles in LDS from global weights, then MFMA phase.

#define NROWS 65536
#define DD 32
#define HH 128
#define NTILE 25  // 8 W1hi + 8 W1lo + 9 W2T(+b2 augmented)

typedef __attribute__((ext_vector_type(8))) short short8;
typedef __attribute__((ext_vector_type(4))) float f32x4;

static __device__ __forceinline__ unsigned short f2bf(float f) {
    unsigned u = __float_as_uint(f);
    u += 0x7fff + ((u >> 16) & 1);  // RNE
    return (unsigned short)(u >> 16);
}
static __device__ __forceinline__ float bf2f(unsigned short h) {
    return __uint_as_float(((unsigned)h) << 16);
}

__global__ __launch_bounds__(512, 4) void stein_fused(
    const float* __restrict__ x, const float* __restrict__ W1,
    const float* __restrict__ b1, const float* __restrict__ W2,
    const float* __restrict__ b2, const float* __restrict__ theta,
    float* __restrict__ out) {
    __shared__ unsigned short lb[NTILE * 512];  // B-fragments: lb[t*512 + l*8 + j]
    __shared__ float cs[HH];                    // c_k
    __shared__ float b1s[HH];

    const int tid = threadIdx.x;
    const int lane = tid & 63;
    const int wv = tid >> 6;       // 8 waves
    const int quad = lane >> 4;
    const int cl = lane & 15;
    const int rowbase = blockIdx.x * 128 + wv * 16;  // 512 blocks * 128 rows

    // Issue this wave's x loads early (A-fragment: A[m=cl][k=quad*8+j]).
    const float* xr = x + (size_t)(rowbase + cl) * DD + quad * 8;
    const float4 x0 = *(const float4*)xr;
    const float4 x1 = *(const float4*)(xr + 4);

    // ---- Pack phase: build B-fragments in LDS from global weights ----
    // Fragment addressing: tile t, column cc=l&15, k=(l>>4)*8+j at
    // lb[t*512 + ((k>>3)*16+cc)*8 + (k&7)]  (matches verified R2 layout).
    if (tid < 256) {
        // W1 column n, k-half `half`: tiles t (hi) and 8+t (lo).
        const int n = tid & 127;
        const int half = tid >> 7;
        const int t = n >> 4, cc = n & 15;
#pragma unroll
        for (int g = 0; g < 2; ++g) {
            const int kg = half * 2 + g;  // k-group of 8
            short8 hi, lo;
#pragma unroll
            for (int j = 0; j < 8; ++j) {
                const float w = W1[(kg * 8 + j) * HH + n];
                const unsigned short h = f2bf(w);
                hi[j] = (short)h;
                lo[j] = (short)f2bf(w - bf2f(h));
            }
            *(short8*)(lb + t * 512 + (kg * 16 + cc) * 8) = hi;
            *(short8*)(lb + (8 + t) * 512 + (kg * 16 + cc) * 8) = lo;
        }
    } else if (tid < 384) {
        // W2 row n -> W2T column n (tile 16+(n>>4)); also c_n.
        const int n = tid - 256;
        const int t2 = 16 + (n >> 4), cc = n & 15;
        float row[32];
        const float4* wr = (const float4*)(W2 + n * DD);
#pragma unroll
        for (int q = 0; q < 8; ++q) {
            const float4 f = wr[q];
            row[4 * q + 0] = f.x;
            row[4 * q + 1] = f.y;
            row[4 * q + 2] = f.z;
            row[4 * q + 3] = f.w;
        }
        float acc = 0.f;
#pragma unroll
        for (int k = 0; k < 32; ++k) acc = fmaf(W1[k * HH + n], row[k], acc);
        cs[n] = acc;
#pragma unroll
        for (int g = 0; g < 4; ++g) {
            short8 v;
#pragma unroll
            for (int j = 0; j < 8; ++j) v[j] = (short)f2bf(row[g * 8 + j]);
            *(short8*)(lb + t2 * 512 + (g * 16 + cc) * 8) = v;
        }
    } else {
        const int u = tid - 384;  // 0..127
        if (u < 16) {
            // Tile 24: col 128+u -> b2 (u==0) else zeros.
#pragma unroll
            for (int g = 0; g < 4; ++g) {
                short8 v;
#pragma unroll
                for (int j = 0; j < 8; ++j)
                    v[j] = (u == 0) ? (short)f2bf(b2[g * 8 + j]) : (short)0;
                *(short8*)(lb + 24 * 512 + (g * 16 + u) * 8) = v;
            }
        }
        b1s[u] = b1[u];
    }
    __syncthreads();

    // ---- MFMA phase ----
    const float xv[8] = {x0.x, x0.y, x0.z, x0.w, x1.x, x1.y, x1.z, x1.w};
    short8 aHi, aLo;
#pragma unroll
    for (int j = 0; j < 8; ++j) {
        const unsigned short h = f2bf(xv[j]);
        aHi[j] = (short)h;
        aLo[j] = (short)f2bf(xv[j] - bf2f(h));
    }

    const f32x4 zero = {0.f, 0.f, 0.f, 0.f};
    float sa[4] = {0.f, 0.f, 0.f, 0.f};

#pragma unroll
    for (int t = 0; t < 8; ++t) {
        const short8 bH = *(const short8*)(lb + t * 512 + lane * 8);
        const short8 bL = *(const short8*)(lb + (8 + t) * 512 + lane * 8);
        const short8 bW = *(const short8*)(lb + (16 + t) * 512 + lane * 8);
        f32x4 z = zero;
        z = __builtin_amdgcn_mfma_f32_16x16x32_bf16(aLo, bH, z, 0, 0, 0);
        z = __builtin_amdgcn_mfma_f32_16x16x32_bf16(aHi, bL, z, 0, 0, 0);
        z = __builtin_amdgcn_mfma_f32_16x16x32_bf16(aHi, bH, z, 0, 0, 0);
        const f32x4 v = __builtin_amdgcn_mfma_f32_16x16x32_bf16(aHi, bW, zero, 0, 0, 0);
        const float ck = cs[t * 16 + cl];
        const float bb = b1s[t * 16 + cl];
#pragma unroll
        for (int r = 0; r < 4; ++r) {
            const float zz = z[r] + bb;
            const float e = __expf(2.f * zz);  // e=inf -> h=1, e=0 -> h=-1: exact
            const float h = fmaf(-2.f, __builtin_amdgcn_rcpf(e + 1.f), 1.f);
            sa[r] += ck - h * fmaf(h, ck, v[r]);  // c_k - h^2 c_k - h v_k
        }
    }
    {  // Augmented tile: v = x.b2 lands in col 128 (cl==0), others exact zero.
        const short8 bW = *(const short8*)(lb + 24 * 512 + lane * 8);
        const f32x4 v = __builtin_amdgcn_mfma_f32_16x16x32_bf16(aHi, bW, zero, 0, 0, 0);
#pragma unroll
        for (int r = 0; r < 4; ++r) sa[r] -= v[r];
    }

    // Reduce over the 16 output columns (cl bits of the lane id).
#pragma unroll
    for (int r = 0; r < 4; ++r) {
#pragma unroll
        for (int m = 1; m < 16; m <<= 1) sa[r] += __shfl_xor(sa[r], m, 64);
    }

    // C/D rows: row = quad*4 + reg -> lane cl==0 stores 4 consecutive rows.
    if (cl == 0) {
        const float th = theta[0];
        float4 o;
        o.x = sa[0] + th;
        o.y = sa[1] + th;
        o.z = sa[2] + th;
        o.w = sa[3] + th;
        *(float4*)(out + rowbase + quad * 4) = o;
    }
}

extern "C" void kernel_launch(void* const* d_in, const int* in_sizes, int n_in,
                              void* d_out, int out_size, void* d_ws, size_t ws_size,
                              hipStream_t stream) {
    const float* x = (const float*)d_in[0];
    const float* W1 = (const float*)d_in[1];
    const float* b1 = (const float*)d_in[2];
    const float* W2 = (const float*)d_in[3];
    const float* b2 = (const float*)d_in[4];
    const float* theta = (const float*)d_in[5];
    float* out = (float*)d_out;

    stein_fused<<<NROWS / 128, 512, 0, stream>>>(x, W1, b1, W2, b2, theta, out);
}